// Round 1
// 1473.963 us; speedup vs baseline: 1.8623x; 1.8623x over previous
//
#include <hip/hip_runtime.h>

// BiLSTM-CRF loss. B=32 L=512 E=1024 H=512 T=32.
// R15: k_lstm h-exchange de-amplification. Theory: R14 was coherent-load
// request-rate bound (~197 req/cy sustained: 32x8B sc1 atomic loads/thread/
// step = 9.4e8 requests). Now: cooperative 32KB fetch per block per step via
// 8x16B global_load_dwordx4 sc1 (2048 req/block-step, 4x fewer), staged into
// LDS (1040B row stride -> <=2-way banks), all 4 waves read B-fragments from
// LDS (kills the 2x duplicate fetch). W fragments lifted to registers (64
// VGPR) so the single 33,280B LDS buffer is reused W-stage -> h-exchange;
// __launch_bounds__(256,4) keeps 4 blocks/CU (1024 blocks co-resident,
// required by the spin protocol). Tag re-poll now exec-masked.
// k_xproj/k_ln/k_emis/k_crf unchanged (absmax 0 since R2).

typedef __attribute__((ext_vector_type(8))) short bf16x8;
typedef __attribute__((ext_vector_type(4))) float f32x4;

#define DEV static __device__ __forceinline__
#define WARM 48
#define GSTEPS 112   // WARM + 64

DEV unsigned short f2bf(float f){
  unsigned int u = __float_as_uint(f);
  u = (u + 0x7fffu + ((u >> 16) & 1u)) >> 16;   // RNE
  return (unsigned short)u;
}
DEV float bf2f(unsigned short h){ return __uint_as_float(((unsigned int)h) << 16); }
DEV float sigm(float x){ return 1.0f / (1.0f + __expf(-x)); }

__global__ void k_sentinel(float* out){ out[0] = -12345.0f; }

__global__ void k_convert(const float* __restrict__ src, unsigned short* __restrict__ dst, int n){
  int i = blockIdx.x * blockDim.x + threadIdx.x;
  int stride = gridDim.x * blockDim.x;
  for (; i < n; i += stride) dst[i] = f2bf(src[i]);
}

// ---- x-projection GEMM, output in recurrence-native layout ----
// out bf16 idx = ((hg*512 + tt)*32 + b)*32 + hl*4 + g   (hg = h>>3, hl = h&7)
__global__ __launch_bounds__(256) void k_xproj(
    const float* __restrict__ X,
    const float* __restrict__ Wf, const float* __restrict__ Wb,
    const float* __restrict__ bf_, const float* __restrict__ bb_,
    unsigned short* __restrict__ xpf, unsigned short* __restrict__ xpb)
{
  const int dir = blockIdx.z;
  const float* W = dir ? Wb : Wf;
  const float* bias = dir ? bb_ : bf_;
  unsigned short* out = dir ? xpb : xpf;
  const int m0 = blockIdx.x * 128;
  const int h0 = blockIdx.y * 32;
  __shared__ unsigned short As[128 * 40];
  __shared__ unsigned short Bs[128 * 40];
  const int tid = threadIdx.x;
  const int lane = tid & 63, w = tid >> 6;
  const int lr = lane & 15, lq = lane >> 4;
  const int wm = (w & 1) * 64, wn = (w >> 1) * 64;

  f32x4 acc[4][4];
  #pragma unroll
  for (int i = 0; i < 4; i++)
    #pragma unroll
    for (int j = 0; j < 4; j++) acc[i][j] = (f32x4){0.f,0.f,0.f,0.f};

  for (int kk = 0; kk < 32; ++kk){
    const int k0 = kk * 32;
    __syncthreads();
    #pragma unroll
    for (int it = 0; it < 2; ++it){
      int c = tid + 256 * it;
      int r = c >> 2, cc = c & 3;
      const float4* xs = (const float4*)&X[(size_t)(m0 + r) * 1024 + k0 + cc * 8];
      float4 a0 = xs[0], a1 = xs[1];
      int wr = ((r & 3) << 9) + h0 + (r >> 2);   // W row for tile col r
      const float4* wsrc = (const float4*)&W[(size_t)wr * 1024 + k0 + cc * 8];
      float4 b0 = wsrc[0], b1 = wsrc[1];
      unsigned short oa[8], ob[8];
      oa[0]=f2bf(a0.x); oa[1]=f2bf(a0.y); oa[2]=f2bf(a0.z); oa[3]=f2bf(a0.w);
      oa[4]=f2bf(a1.x); oa[5]=f2bf(a1.y); oa[6]=f2bf(a1.z); oa[7]=f2bf(a1.w);
      ob[0]=f2bf(b0.x); ob[1]=f2bf(b0.y); ob[2]=f2bf(b0.z); ob[3]=f2bf(b0.w);
      ob[4]=f2bf(b1.x); ob[5]=f2bf(b1.y); ob[6]=f2bf(b1.z); ob[7]=f2bf(b1.w);
      *(uint4*)&As[r * 40 + cc * 8] = *(const uint4*)oa;
      *(uint4*)&Bs[r * 40 + cc * 8] = *(const uint4*)ob;
    }
    __syncthreads();
    bf16x8 a[4], b[4];
    #pragma unroll
    for (int i = 0; i < 4; i++) a[i] = *(const bf16x8*)&As[(wm + i * 16 + lr) * 40 + lq * 8];
    #pragma unroll
    for (int j = 0; j < 4; j++) b[j] = *(const bf16x8*)&Bs[(wn + j * 16 + lr) * 40 + lq * 8];
    #pragma unroll
    for (int i = 0; i < 4; i++)
      #pragma unroll
      for (int j = 0; j < 4; j++)
        acc[i][j] = __builtin_amdgcn_mfma_f32_16x16x32_bf16(a[i], b[j], acc[i][j], 0, 0, 0);
  }
  #pragma unroll
  for (int i = 0; i < 4; i++){
    #pragma unroll
    for (int j = 0; j < 4; j++){
      int c = wn + j * 16 + lr;
      int realcol = ((c & 3) << 9) + h0 + (c >> 2);
      float bv = bias[realcol];
      int wgG = (h0 + (c >> 2)) >> 3;
      int inner = c & 31;
      #pragma unroll
      for (int r = 0; r < 4; r++){
        int row = m0 + wm + i * 16 + lq * 4 + r;
        int b_ = row >> 9, tt = row & 511;
        out[((size_t)(wgG * 512 + tt) * 32 + b_) * 32 + inner] = f2bf(acc[i][j][r] + bv);
      }
    }
  }
}

// ---- persistent chunked bidirectional LSTM recurrence ----
// 1024 blocks: group = bid>>6 (0..15) = chunk*2 + dir; wg = bid&63 owns
// h-lanes [wg*8, wg*8+8). Each group scans its 64-t chunk with WARM extra
// steps from h=c=0 (discarded). Protocol per group identical to R9:
// relaxed agent atomics, tag after vmcnt(0)+barrier, 64 tags/group.
// R15: per step, h(t-1) is fetched ONCE per block (32KB, 8x16B sc1 loads
// per thread) into LDS; MFMA B-fragments come from LDS, A-fragments live
// in registers (loaded once at start through the same LDS buffer).
__global__ __launch_bounds__(256, 4) void k_lstm(
    const unsigned short* __restrict__ xpf, const unsigned short* __restrict__ xpb,
    const float* __restrict__ whhf, const float* __restrict__ whhb,
    unsigned long long* __restrict__ hpub,   // [group][GSTEPS][b][h/4] u64
    unsigned int* __restrict__ tags,          // [group][64] tags, 64B stride
    unsigned int* __restrict__ tflag)
{
  const int bid = blockIdx.x;
  const int group = bid >> 6;
  const int wg    = bid & 63;
  const int chunk = group >> 1;
  const int dir   = group & 1;
  const int c0 = chunk * 64;
  int tstart, nsteps;
  if (dir == 0){
    tstart = c0 - WARM; if (tstart < 0) tstart = 0;
    nsteps = c0 + 64 - tstart;
  } else {
    tstart = c0 + 63 + WARM; if (tstart > 511) tstart = 511;
    nsteps = tstart - c0 + 1;
  }
  const int hi0 = wg * 8;
  const unsigned short* xp  = dir ? xpb  : xpf;
  const float* whh = dir ? whhb : whhf;
  unsigned int* tagsd = tags + group * 64 * 16;   // u32 stride 16 = 64B
  unsigned long long* hp = hpub + (size_t)group * (GSTEPS * 4096);

  // 33,280 B: W-stage (32 rows x 520 u16) first, then per-step h exchange
  // (32 batch-rows x 1040 B; 1024 B payload + 16 B pad -> <=2-way banks).
  __shared__ unsigned char smem[32 * 1040];

  const int tid = threadIdx.x;
  const int lane = tid & 63, w = tid >> 6;
  const int lr = lane & 15, lq = lane >> 4;
  const int tm = w & 1, tn = w >> 1;
  const int myb = tn * 16 + lr;     // owned batch
  const int myh = tm * 4 + lq;      // owned h-lane within slice [0,8)

  // one-time: stage w_hh slice fp32->bf16 into LDS, rows interleaved h*4+gate
  {
    unsigned short* Ws = (unsigned short*)smem;
    #pragma unroll
    for (int it = 0; it < 8; ++it){
      int c = tid + 256 * it;
      int r = c >> 6, cc = c & 63;
      int ng = (r & 3) * 512 + hi0 + ((r >> 4) << 2) + ((r >> 2) & 3);
      const float4* src = (const float4*)&whh[(size_t)ng * 512 + cc * 8];
      float4 f0 = src[0], f1 = src[1];
      unsigned short o[8];
      o[0]=f2bf(f0.x); o[1]=f2bf(f0.y); o[2]=f2bf(f0.z); o[3]=f2bf(f0.w);
      o[4]=f2bf(f1.x); o[5]=f2bf(f1.y); o[6]=f2bf(f1.z); o[7]=f2bf(f1.w);
      *(uint4*)&Ws[r * 520 + cc * 8] = *(const uint4*)o;
    }
  }
  __syncthreads();
  // lift this wave's 16 A-fragments into registers (64 VGPR, live all-kernel)
  bf16x8 wreg[16];
  #pragma unroll
  for (int kk = 0; kk < 16; ++kk)
    wreg[kk] = *(const bf16x8*)&smem[(tm * 16 + lr) * 1040 + kk * 64 + lq * 16];
  __syncthreads();

  const unsigned long long* xq = (const unsigned long long*)xp;
  float creg = 0.0f;

  for (int s = 0; s < nsteps; ++s){
    const int tt = dir ? (tstart - s) : (tstart + s);
    // prefetch x gates: one u64 = (i,f,g,o) for (myb, myh)
    unsigned long long g4 = xq[((size_t)(wg * 512 + tt) * 32 + myb) * 8 + myh];
    float xi = bf2f((unsigned short)(g4 & 0xFFFF));
    float xf = bf2f((unsigned short)((g4 >> 16) & 0xFFFF));
    float xg = bf2f((unsigned short)((g4 >> 32) & 0xFFFF));
    float xo = bf2f((unsigned short)(g4 >> 48));
    float gi = 0.f, gf = 0.f, gg = 0.f, go = 0.f;

    if (s > 0){
      if (w == 0){
        const unsigned int target = (unsigned int)s;
        int spins = 0;
        unsigned int v = __hip_atomic_load(&tagsd[lane * 16],
                                           __ATOMIC_RELAXED, __HIP_MEMORY_SCOPE_AGENT);
        while (__ballot(v < target) != 0ull){
          if (++spins > (1 << 15)){
            if (lane == 0)
              __hip_atomic_fetch_add(tflag, 1u, __ATOMIC_RELAXED, __HIP_MEMORY_SCOPE_AGENT);
            break;
          }
          __builtin_amdgcn_s_sleep(1);
          if (v < target)   // exec-masked re-poll: satisfied lanes stop loading
            v = __hip_atomic_load(&tagsd[lane * 16],
                                  __ATOMIC_RELAXED, __HIP_MEMORY_SCOPE_AGENT);
        }
      }
      __syncthreads();
      // cooperative coherent fetch of h(t-1): 32KB/block, 8x16B per thread.
      // u128 index c = it*256 + tid: row = c>>6 = 4*it + w (wave-uniform),
      // slot = c&63 = lane. sc1 = agent scope (bypass L1+XCD-L2, hit L3).
      const unsigned char* hsrc = (const unsigned char*)(hp + (size_t)(s - 1) * 4096);
      uint4 hbuf[8];
      #pragma unroll
      for (int it = 0; it < 8; ++it){
        const void* p = hsrc + (size_t)(it * 256 + tid) * 16;
        asm volatile("global_load_dwordx4 %0, %1, off sc1"
                     : "=v"(hbuf[it]) : "v"(p));
      }
      asm volatile("s_waitcnt vmcnt(0)" ::: "memory");
      #pragma unroll
      for (int it = 0; it < 8; ++it)
        *(uint4*)&smem[(it * 4 + w) * 1040 + lane * 16] = hbuf[it];
      __syncthreads();
      // B-fragments from LDS: byte = myb*1040 + kk*64 + lq*16
      f32x4 acc = (f32x4){0.f,0.f,0.f,0.f};
      #pragma unroll
      for (int kk = 0; kk < 16; ++kk){
        bf16x8 b = *(const bf16x8*)&smem[myb * 1040 + kk * 64 + lq * 16];
        acc = __builtin_amdgcn_mfma_f32_16x16x32_bf16(wreg[kk], b, acc, 0, 0, 0);
      }
      gi = acc[0]; gf = acc[1]; gg = acc[2]; go = acc[3];
    }

    float iv = sigm(xi + gi), fv = sigm(xf + gf);
    float gv = tanhf(xg + gg), ov = sigm(xo + go);
    creg = fv * creg + iv * gv;
    float hv = ov * tanhf(creg);

    // shuffle-pack: u64 = h[myh=tm*4+0..3] for batch myb, valid in lq==0
    unsigned int hu = (unsigned int)f2bf(hv);
    unsigned int p32 = hu | (((unsigned int)__shfl_xor((int)hu, 16)) << 16);
    unsigned int hi32 = (unsigned int)__shfl_xor((int)p32, 32);
    unsigned long long p64 = ((unsigned long long)hi32 << 32) | (unsigned long long)p32;
    if (lq == 0){
      __hip_atomic_store(&hp[(size_t)s * 4096 + (size_t)myb * 128 + wg * 2 + tm],
                         p64, __ATOMIC_RELAXED, __HIP_MEMORY_SCOPE_AGENT);
    }
    asm volatile("s_waitcnt vmcnt(0)" ::: "memory");  // data at coherence point
    __syncthreads();
    if (tid == 0)
      __hip_atomic_store(&tagsd[wg * 16], (unsigned int)(s + 1),
                         __ATOMIC_RELAXED, __HIP_MEMORY_SCOPE_AGENT);
  }
}

// ---- LayerNorm: wave per (b,t) row; reads hpub (chunked layout), writes hnorm ----
__global__ __launch_bounds__(256) void k_ln(
    const unsigned short* __restrict__ hbuf,
    const float* __restrict__ g, const float* __restrict__ bta,
    unsigned short* __restrict__ hnorm)
{
  int row = blockIdx.x * 4 + (threadIdx.x >> 6);
  int lane = threadIdx.x & 63;
  int b = row >> 9, t = row & 511;
  const int ch = t >> 6;
  // fwd: group 2*ch, local step = t - max(0, ch*64-WARM)
  int tsf = ch * 64 - WARM; if (tsf < 0) tsf = 0;
  const int gf = ch * 2, sf = t - tsf;
  // bwd: group 2*ch+1, local step = min(511, ch*64+63+WARM) - t
  int tsb = ch * 64 + 63 + WARM; if (tsb > 511) tsb = 511;
  const int gb = ch * 2 + 1, sb = tsb - t;
  const unsigned short* fsrc = hbuf + (((size_t)(gf * GSTEPS + sf) * 32 + b) * 512);
  const unsigned short* bsrc = hbuf + (((size_t)(gb * GSTEPS + sb) * 32 + b) * 512);
  uint4 u0 = *(const uint4*)&fsrc[lane * 8];
  uint4 u1 = *(const uint4*)&bsrc[lane * 8];
  const unsigned short* p0 = (const unsigned short*)&u0;
  const unsigned short* p1 = (const unsigned short*)&u1;
  float x[16];
  float sum = 0.f, ssq = 0.f;
  #pragma unroll
  for (int j = 0; j < 8; j++){ x[j] = bf2f(p0[j]); x[8 + j] = bf2f(p1[j]); }
  #pragma unroll
  for (int j = 0; j < 16; j++){ sum += x[j]; ssq += x[j] * x[j]; }
  #pragma unroll
  for (int off = 32; off; off >>= 1){ sum += __shfl_xor(sum, off); ssq += __shfl_xor(ssq, off); }
  float mean = sum * (1.0f / 1024.0f);
  float var = ssq * (1.0f / 1024.0f) - mean * mean;
  float rstd = rsqrtf(var + 1e-5f);
  unsigned short* dst = hnorm + (size_t)row * 1024;
  unsigned short o0[8], o1[8];
  #pragma unroll
  for (int j = 0; j < 8; j++){
    int i0 = lane * 8 + j, i1 = 512 + lane * 8 + j;
    o0[j] = f2bf((x[j]     - mean) * rstd * g[i0] + bta[i0]);
    o1[j] = f2bf((x[8 + j] - mean) * rstd * g[i1] + bta[i1]);
  }
  *(uint4*)&dst[lane * 8]       = *(const uint4*)o0;
  *(uint4*)&dst[512 + lane * 8] = *(const uint4*)o1;
}

// ---- emissions GEMM: (16384x1024)@(1024x32) + b_tag, no LDS, direct fragments ----
__global__ __launch_bounds__(256) void k_emis(
    const unsigned short* __restrict__ hnorm,
    const unsigned short* __restrict__ wtag,
    const float* __restrict__ btag,
    float* __restrict__ emis)
{
  const int m0 = blockIdx.x * 128;
  const int tid = threadIdx.x;
  const int lane = tid & 63, w = tid >> 6;
  const int lr = lane & 15, lq = lane >> 4;
  f32x4 acc[2][2];
  #pragma unroll
  for (int i = 0; i < 2; i++)
    #pragma unroll
    for (int j = 0; j < 2; j++) acc[i][j] = (f32x4){0.f,0.f,0.f,0.f};

  for (int kk = 0; kk < 32; ++kk){
    const int k0 = kk * 32;
    bf16x8 a[2], b[2];
    #pragma unroll
    for (int i = 0; i < 2; i++)
      a[i] = *(const bf16x8*)&hnorm[(size_t)(m0 + w * 32 + i * 16 + lr) * 1024 + k0 + lq * 8];
    #pragma unroll
    for (int j = 0; j < 2; j++)
      b[j] = *(const bf16x8*)&wtag[(size_t)(j * 16 + lr) * 1024 + k0 + lq * 8];
    #pragma unroll
    for (int i = 0; i < 2; i++)
      #pragma unroll
      for (int j = 0; j < 2; j++)
        acc[i][j] = __builtin_amdgcn_mfma_f32_16x16x32_bf16(a[i], b[j], acc[i][j], 0, 0, 0);
  }
  #pragma unroll
  for (int i = 0; i < 2; i++)
    #pragma unroll
    for (int j = 0; j < 2; j++){
      int col = j * 16 + lr;
      float bv = btag[col];
      #pragma unroll
      for (int r = 0; r < 4; r++){
        int row = m0 + w * 32 + i * 16 + lq * 4 + r;
        emis[(size_t)row * 32 + col] = acc[i][j][r] + bv;
      }
    }
}

// ---- CRF log-likelihood (wave per batch) ----
__global__ __launch_bounds__(64) void k_crf(
    const float* __restrict__ emis, const int* __restrict__ tags,
    const int* __restrict__ mask, const float* __restrict__ trans,
    const float* __restrict__ start_t, const float* __restrict__ end_t,
    float* __restrict__ llh)
{
  const int b = blockIdx.x;
  const int lane = threadIdx.x;
  __shared__ float tr[32 * 33];
  __shared__ float al[32];
  #pragma unroll
  for (int it = 0; it < 16; ++it){
    int c = lane + 64 * it;
    tr[(c >> 5) * 33 + (c & 31)] = trans[c];
  }
  __syncthreads();
  float part = 0.0f; int cnt = 0;
  for (int t = lane; t < 512; t += 64){
    int tg = tags[b * 512 + t];
    cnt += mask[b * 512 + t];
    if (t == 0){
      part += start_t[tg] + emis[((size_t)b * 512) * 32 + tg];
    } else {
      int tp = tags[b * 512 + t - 1];
      float mf = (float)mask[b * 512 + t];
      part += (tr[tp * 33 + tg] + emis[((size_t)b * 512 + t) * 32 + tg]) * mf;
    }
  }
  #pragma unroll
  for (int off = 32; off; off >>= 1){ part += __shfl_xor(part, off); cnt += __shfl_xor(cnt, off); }
  int col = lane & 31;
  if (lane < 32) al[lane] = start_t[lane] + emis[((size_t)b * 512) * 32 + lane];
  __syncthreads();
  for (int t = 1; t < 512; ++t){
    float e = emis[((size_t)b * 512 + t) * 32 + col];
    int mk = mask[b * 512 + t];
    float m = -1e30f;
    #pragma unroll
    for (int i = 0; i < 32; i++) m = fmaxf(m, al[i] + tr[i * 33 + col]);
    float sexp = 0.0f;
    #pragma unroll
    for (int i = 0; i < 32; i++) sexp += __expf(al[i] + tr[i * 33 + col] - m);
    float nxt = e + m + __logf(sexp);
    float na = mk ? nxt : al[col];
    __syncthreads();
    if (lane < 32) al[lane] = na;
    __syncthreads();
  }
  float v = (lane < 32) ? (al[lane] + end_t[lane]) : -1e30f;
  float mv = v;
  #pragma unroll
  for (int off = 32; off; off >>= 1) mv = fmaxf(mv, __shfl_xor(mv, off));
  float se = (lane < 32) ? __expf(v - mv) : 0.0f;
  #pragma unroll
  for (int off = 32; off; off >>= 1) se += __shfl_xor(se, off);
  if (lane == 0){
    int last_idx = cnt - 1;
    int lt = tags[b * 512 + last_idx];
    float num = part + end_t[lt];
    float logZ = mv + __logf(se);
    llh[b] = num - logZ;
  }
}

__global__ void k_final(const float* __restrict__ llh, const unsigned int* __restrict__ tflag,
                        float* __restrict__ out){
  int lane = threadIdx.x;
  float v = (lane < 32) ? llh[lane] : 0.0f;
  #pragma unroll
  for (int off = 32; off; off >>= 1) v += __shfl_xor(v, off);
  if (lane == 0) out[0] = -(v * (1.0f / 32.0f)) + (tflag[0] ? 1.0e6f : 0.0f);
}

extern "C" void kernel_launch(void* const* d_in, const int* in_sizes, int n_in,
                              void* d_out, int out_size, void* d_ws, size_t ws_size,
                              hipStream_t stream)
{
  (void)in_sizes; (void)n_in; (void)out_size;
  const float* emb   = (const float*)d_in[0];
  const int*   tags  = (const int*)d_in[1];
  const int*   amask = (const int*)d_in[2];
  const float* wihf  = (const float*)d_in[3];
  const float* whhf  = (const float*)d_in[4];
  const float* bf_   = (const float*)d_in[5];
  const float* wihb  = (const float*)d_in[6];
  const float* whhb  = (const float*)d_in[7];
  const float* bb_   = (const float*)d_in[8];
  const float* lng   = (const float*)d_in[9];
  const float* lnb   = (const float*)d_in[10];
  const float* wtag  = (const float*)d_in[11];
  const float* btag  = (const float*)d_in[12];
  const float* trans = (const float*)d_in[13];
  const float* stt   = (const float*)d_in[14];
  const float* endt  = (const float*)d_in[15];

  unsigned char* wsp = (unsigned char*)d_ws;
  size_t off = 0;
  auto alloc = [&](size_t bytes) -> void* {
    void* p = wsp + off; off += (bytes + 255) & ~(size_t)255; return p;
  };
  unsigned short* xpf   = (unsigned short*)alloc(33554432ull * 2);  // 64MB, reused as hnorm
  unsigned short* xpb   = (unsigned short*)alloc(33554432ull * 2);  // 64MB
  unsigned long long* hpub = (unsigned long long*)alloc(16ull * GSTEPS * 4096 * 8);  // ~58.7MB
  unsigned short* wtagb = (unsigned short*)alloc(32768ull * 2);
  float* emis = (float*)alloc(524288ull * 4);
  float* llh  = (float*)alloc(64 * 4);
  unsigned int* sync = (unsigned int*)alloc(16 * 64 * 64 + 256);  // [group][64] 64B tags + tflag
  unsigned short* hnorm = xpf;  // alias: xp dead after k_lstm
  unsigned int* tflag = sync + 16 * 64 * 16;

  if (off > ws_size){
    k_sentinel<<<1, 1, 0, stream>>>((float*)d_out);
    return;
  }

  hipMemsetAsync(sync, 0, 16 * 64 * 64 + 256, stream);
  k_convert<<<32, 256, 0, stream>>>(wtag, wtagb, 32768);
  k_xproj<<<dim3(128, 16, 2), 256, 0, stream>>>(emb, wihf, wihb, bf_, bb_, xpf, xpb);
  k_lstm<<<1024, 256, 0, stream>>>(xpf, xpb, whhf, whhb, hpub, sync, tflag);
  k_ln<<<4096, 256, 0, stream>>>((const unsigned short*)hpub, lng, lnb, hnorm);
  k_emis<<<128, 256, 0, stream>>>(hnorm, wtagb, btag, emis);
  k_crf<<<32, 64, 0, stream>>>(emis, tags, amask, trans, stt, endt, llh);
  k_final<<<1, 64, 0, stream>>>(llh, tflag, (float*)d_out);
}

// Round 2
// 1260.727 us; speedup vs baseline: 2.1772x; 1.1691x over previous
//
#include <hip/hip_runtime.h>

// BiLSTM-CRF loss. B=32 L=512 E=1024 H=512 T=32.
// R16: (a) k_lstm 4x fewer/fatter blocks: 16 blocks/group x 32 h-lanes
// (256 blocks x 256 thr). Coherent fetch requests/step 2.1e6 -> 5.2e5
// (request-rate ~200/cy was the R15 limiter); per-CU LDS read traffic
// halves; tag fan-in 64->16. W fragments in 128 VGPR (one-time load),
// protocol identical to R9/R15 (relaxed agent atomics, vmcnt(0)+barrier
// then tag). hpub layout unchanged -> k_ln untouched. (b) k_xproj now
// consumes pre-converted bf16 X/W (vectorized k_convert8, buffers aliased
// into hpub which is dead until k_lstm) -> staging is pure copy, no
// per-tile f2bf VALU storm, half the staged bytes. Bit-identical math.

typedef __attribute__((ext_vector_type(8))) short bf16x8;
typedef __attribute__((ext_vector_type(4))) float f32x4;

#define DEV static __device__ __forceinline__
#define WARM 48
#define GSTEPS 112   // WARM + 64

DEV unsigned short f2bf(float f){
  unsigned int u = __float_as_uint(f);
  u = (u + 0x7fffu + ((u >> 16) & 1u)) >> 16;   // RNE
  return (unsigned short)u;
}
DEV float bf2f(unsigned short h){ return __uint_as_float(((unsigned int)h) << 16); }
DEV float sigm(float x){ return 1.0f / (1.0f + __expf(-x)); }

__global__ void k_sentinel(float* out){ out[0] = -12345.0f; }

// vectorized fp32 -> bf16 (8 elems/thread/iter)
__global__ void k_convert8(const float* __restrict__ src, unsigned short* __restrict__ dst, int n8){
  int i = blockIdx.x * blockDim.x + threadIdx.x;
  int stride = gridDim.x * blockDim.x;
  for (; i < n8; i += stride){
    const float4* s4 = (const float4*)&src[(size_t)i * 8];
    float4 f0 = s4[0], f1 = s4[1];
    unsigned short o[8];
    o[0]=f2bf(f0.x); o[1]=f2bf(f0.y); o[2]=f2bf(f0.z); o[3]=f2bf(f0.w);
    o[4]=f2bf(f1.x); o[5]=f2bf(f1.y); o[6]=f2bf(f1.z); o[7]=f2bf(f1.w);
    *(uint4*)&dst[(size_t)i * 8] = *(const uint4*)o;
  }
}

// ---- x-projection GEMM (bf16 inputs), output in recurrence-native layout ----
// out bf16 idx = ((hg*512 + tt)*32 + b)*32 + hl*4 + g   (hg = h>>3, hl = h&7)
__global__ __launch_bounds__(256) void k_xproj(
    const unsigned short* __restrict__ Xb,
    const unsigned short* __restrict__ Wfb, const unsigned short* __restrict__ Wbb,
    const float* __restrict__ bf_, const float* __restrict__ bb_,
    unsigned short* __restrict__ xpf, unsigned short* __restrict__ xpb)
{
  const int dir = blockIdx.z;
  const unsigned short* W = dir ? Wbb : Wfb;
  const float* bias = dir ? bb_ : bf_;
  unsigned short* out = dir ? xpb : xpf;
  const int m0 = blockIdx.x * 128;
  const int h0 = blockIdx.y * 32;
  __shared__ unsigned short As[128 * 40];
  __shared__ unsigned short Bs[128 * 40];
  const int tid = threadIdx.x;
  const int lane = tid & 63, w = tid >> 6;
  const int lr = lane & 15, lq = lane >> 4;
  const int wm = (w & 1) * 64, wn = (w >> 1) * 64;

  f32x4 acc[4][4];
  #pragma unroll
  for (int i = 0; i < 4; i++)
    #pragma unroll
    for (int j = 0; j < 4; j++) acc[i][j] = (f32x4){0.f,0.f,0.f,0.f};

  for (int kk = 0; kk < 32; ++kk){
    const int k0 = kk * 32;
    __syncthreads();
    #pragma unroll
    for (int it = 0; it < 2; ++it){
      int c = tid + 256 * it;
      int r = c >> 2, cc = c & 3;
      uint4 av = *(const uint4*)&Xb[(size_t)(m0 + r) * 1024 + k0 + cc * 8];
      int wr = ((r & 3) << 9) + h0 + (r >> 2);   // W row for tile col r
      uint4 bv = *(const uint4*)&W[(size_t)wr * 1024 + k0 + cc * 8];
      *(uint4*)&As[r * 40 + cc * 8] = av;
      *(uint4*)&Bs[r * 40 + cc * 8] = bv;
    }
    __syncthreads();
    bf16x8 a[4], b[4];
    #pragma unroll
    for (int i = 0; i < 4; i++) a[i] = *(const bf16x8*)&As[(wm + i * 16 + lr) * 40 + lq * 8];
    #pragma unroll
    for (int j = 0; j < 4; j++) b[j] = *(const bf16x8*)&Bs[(wn + j * 16 + lr) * 40 + lq * 8];
    #pragma unroll
    for (int i = 0; i < 4; i++)
      #pragma unroll
      for (int j = 0; j < 4; j++)
        acc[i][j] = __builtin_amdgcn_mfma_f32_16x16x32_bf16(a[i], b[j], acc[i][j], 0, 0, 0);
  }
  #pragma unroll
  for (int i = 0; i < 4; i++){
    #pragma unroll
    for (int j = 0; j < 4; j++){
      int c = wn + j * 16 + lr;
      int realcol = ((c & 3) << 9) + h0 + (c >> 2);
      float bv = bias[realcol];
      int wgG = (h0 + (c >> 2)) >> 3;
      int inner = c & 31;
      #pragma unroll
      for (int r = 0; r < 4; r++){
        int row = m0 + wm + i * 16 + lq * 4 + r;
        int b_ = row >> 9, tt = row & 511;
        out[((size_t)(wgG * 512 + tt) * 32 + b_) * 32 + inner] = f2bf(acc[i][j][r] + bv);
      }
    }
  }
}

// ---- persistent chunked bidirectional LSTM recurrence ----
// 256 blocks: group = bid>>4 (0..15) = chunk*2 + dir; wg = bid&15 owns
// h-lanes [wg*32, wg*32+32). Per step: cooperative 32KB coherent fetch of
// h(t-1) (8x16B sc1 loads/thread) into LDS; 4 waves each run 2x2 MFMA
// tiles (K=512, 64 MFMA/wave) with W in 128 VGPRs. Each thread owns 4
// LSTM cells (2 h x 2 b). Tag protocol: 16 tags/group, producer stores
// tag after vmcnt(0)+barrier (R9 semantics).
__global__ __launch_bounds__(256, 2) void k_lstm(
    const unsigned short* __restrict__ xpf, const unsigned short* __restrict__ xpb,
    const float* __restrict__ whhf, const float* __restrict__ whhb,
    unsigned long long* __restrict__ hpub,   // [group][GSTEPS][b][h/4] u64
    unsigned int* __restrict__ tags,          // [group][16] tags, 64B stride
    unsigned int* __restrict__ tflag)
{
  const int bid = blockIdx.x;
  const int group = bid >> 4;
  const int wg    = bid & 15;
  const int chunk = group >> 1;
  const int dir   = group & 1;
  const int c0 = chunk * 64;
  int tstart, nsteps;
  if (dir == 0){
    tstart = c0 - WARM; if (tstart < 0) tstart = 0;
    nsteps = c0 + 64 - tstart;
  } else {
    tstart = c0 + 63 + WARM; if (tstart > 511) tstart = 511;
    nsteps = tstart - c0 + 1;
  }
  const int hi0 = wg * 32;
  const unsigned short* xp  = dir ? xpb  : xpf;
  const float* whh = dir ? whhb : whhf;
  unsigned int* tagsd = tags + group * 64 * 16;   // u32 stride 16 = 64B
  unsigned long long* hp = hpub + (size_t)group * (GSTEPS * 4096);

  // h-exchange buffer: 32 batch-rows x 1040 B (1024 payload + 16 pad)
  __shared__ unsigned char smem[32 * 1040];

  const int tid = threadIdx.x;
  const int lane = tid & 63, w = tid >> 6;     // w in 0..3
  const int lr = lane & 15, lq = lane >> 4;

  // one-time: W fragments global fp32 -> bf16 registers.
  // wave w owns gate-rows m_local in [w*32, w*32+32), 2 m-tiles of 16.
  // fragment row lr -> W row (lr&3)*512 + hi0 + w*8 + i*4 + (lr>>2).
  bf16x8 wreg[2][16];
  #pragma unroll
  for (int i = 0; i < 2; ++i){
    const int m_local = w * 32 + i * 16 + lr;
    const int wrow = (m_local & 3) * 512 + hi0 + (m_local >> 2);
    const float* wsrc = &whh[(size_t)wrow * 512 + lq * 8];
    #pragma unroll
    for (int kk = 0; kk < 16; ++kk){
      float4 f0 = *(const float4*)&wsrc[kk * 32];
      float4 f1 = *(const float4*)&wsrc[kk * 32 + 4];
      unsigned short o[8];
      o[0]=f2bf(f0.x); o[1]=f2bf(f0.y); o[2]=f2bf(f0.z); o[3]=f2bf(f0.w);
      o[4]=f2bf(f1.x); o[5]=f2bf(f1.y); o[6]=f2bf(f1.z); o[7]=f2bf(f1.w);
      wreg[i][kk] = *(const bf16x8*)o;
    }
  }

  // this thread's 4 cells: h_i = hi0 + w*8 + i*4 + lq (i=0,1),
  // b_j = j*16 + lr (j=0,1).  hg = (hi0+w*8+..)>>3 = wg*4 + w (uniform).
  const int hg = wg * 4 + w;
  const unsigned long long* xq = (const unsigned long long*)xp;
  float c00 = 0.f, c01 = 0.f, c10 = 0.f, c11 = 0.f;

  for (int s = 0; s < nsteps; ++s){
    const int tt = dir ? (tstart - s) : (tstart + s);
    const size_t xrow = (size_t)(hg * 512 + tt) * 32;
    unsigned long long g00 = xq[(xrow + lr) * 8 + lq];        // i=0, b=lr
    unsigned long long g01 = xq[(xrow + 16 + lr) * 8 + lq];   // i=0, b=16+lr
    unsigned long long g10 = xq[(xrow + lr) * 8 + 4 + lq];    // i=1, b=lr
    unsigned long long g11 = xq[(xrow + 16 + lr) * 8 + 4 + lq];
    f32x4 a00 = (f32x4){0.f,0.f,0.f,0.f}, a01 = a00, a10 = a00, a11 = a00;

    if (s > 0){
      if (w == 0){
        const unsigned int target = (unsigned int)s;
        unsigned int v = target;
        if (lane < 16)
          v = __hip_atomic_load(&tagsd[lane * 16],
                                __ATOMIC_RELAXED, __HIP_MEMORY_SCOPE_AGENT);
        int spins = 0;
        while (__ballot(v < target) != 0ull){
          if (++spins > (1 << 15)){
            if (lane == 0)
              __hip_atomic_fetch_add(tflag, 1u, __ATOMIC_RELAXED, __HIP_MEMORY_SCOPE_AGENT);
            break;
          }
          __builtin_amdgcn_s_sleep(1);
          if (v < target)
            v = __hip_atomic_load(&tagsd[lane * 16],
                                  __ATOMIC_RELAXED, __HIP_MEMORY_SCOPE_AGENT);
        }
      }
      __syncthreads();
      // cooperative coherent fetch of h(t-1): 32KB/block, 8x16B per thread.
      // u128 index c = it*256 + tid: row = it*4 + w (wave-uniform), slot = lane.
      const unsigned char* hsrc = (const unsigned char*)(hp + (size_t)(s - 1) * 4096);
      uint4 hbuf[8];
      #pragma unroll
      for (int it = 0; it < 8; ++it){
        const void* p = hsrc + (size_t)(it * 256 + tid) * 16;
        asm volatile("global_load_dwordx4 %0, %1, off sc1"
                     : "=v"(hbuf[it]) : "v"(p));
      }
      asm volatile("s_waitcnt vmcnt(0)" ::: "memory");
      #pragma unroll
      for (int it = 0; it < 8; ++it)
        *(uint4*)&smem[(it * 4 + w) * 1040 + lane * 16] = hbuf[it];
      __syncthreads();
      #pragma unroll
      for (int kk = 0; kk < 16; ++kk){
        bf16x8 b0 = *(const bf16x8*)&smem[lr * 1040 + kk * 64 + lq * 16];
        bf16x8 b1 = *(const bf16x8*)&smem[(16 + lr) * 1040 + kk * 64 + lq * 16];
        a00 = __builtin_amdgcn_mfma_f32_16x16x32_bf16(wreg[0][kk], b0, a00, 0, 0, 0);
        a01 = __builtin_amdgcn_mfma_f32_16x16x32_bf16(wreg[0][kk], b1, a01, 0, 0, 0);
        a10 = __builtin_amdgcn_mfma_f32_16x16x32_bf16(wreg[1][kk], b0, a10, 0, 0, 0);
        a11 = __builtin_amdgcn_mfma_f32_16x16x32_bf16(wreg[1][kk], b1, a11, 0, 0, 0);
      }
    }

    float h00, h01, h10, h11;
    {
      float xi, xf, xg, xo, iv, fv, gv, ov;
      xi = bf2f((unsigned short)(g00 & 0xFFFF));
      xf = bf2f((unsigned short)((g00 >> 16) & 0xFFFF));
      xg = bf2f((unsigned short)((g00 >> 32) & 0xFFFF));
      xo = bf2f((unsigned short)(g00 >> 48));
      iv = sigm(xi + a00[0]); fv = sigm(xf + a00[1]);
      gv = tanhf(xg + a00[2]); ov = sigm(xo + a00[3]);
      c00 = fv * c00 + iv * gv; h00 = ov * tanhf(c00);

      xi = bf2f((unsigned short)(g01 & 0xFFFF));
      xf = bf2f((unsigned short)((g01 >> 16) & 0xFFFF));
      xg = bf2f((unsigned short)((g01 >> 32) & 0xFFFF));
      xo = bf2f((unsigned short)(g01 >> 48));
      iv = sigm(xi + a01[0]); fv = sigm(xf + a01[1]);
      gv = tanhf(xg + a01[2]); ov = sigm(xo + a01[3]);
      c01 = fv * c01 + iv * gv; h01 = ov * tanhf(c01);

      xi = bf2f((unsigned short)(g10 & 0xFFFF));
      xf = bf2f((unsigned short)((g10 >> 16) & 0xFFFF));
      xg = bf2f((unsigned short)((g10 >> 32) & 0xFFFF));
      xo = bf2f((unsigned short)(g10 >> 48));
      iv = sigm(xi + a10[0]); fv = sigm(xf + a10[1]);
      gv = tanhf(xg + a10[2]); ov = sigm(xo + a10[3]);
      c10 = fv * c10 + iv * gv; h10 = ov * tanhf(c10);

      xi = bf2f((unsigned short)(g11 & 0xFFFF));
      xf = bf2f((unsigned short)((g11 >> 16) & 0xFFFF));
      xg = bf2f((unsigned short)((g11 >> 32) & 0xFFFF));
      xo = bf2f((unsigned short)(g11 >> 48));
      iv = sigm(xi + a11[0]); fv = sigm(xf + a11[1]);
      gv = tanhf(xg + a11[2]); ov = sigm(xo + a11[3]);
      c11 = fv * c11 + iv * gv; h11 = ov * tanhf(c11);
    }

    // shuffle-pack per (i,j): u64 = h[lq=0..3], valid in lq==0
    unsigned int hu, p32, hi32;
    unsigned long long p00, p01, p10, p11;
    hu = (unsigned int)f2bf(h00);
    p32 = hu | (((unsigned int)__shfl_xor((int)hu, 16)) << 16);
    hi32 = (unsigned int)__shfl_xor((int)p32, 32);
    p00 = ((unsigned long long)hi32 << 32) | (unsigned long long)p32;
    hu = (unsigned int)f2bf(h01);
    p32 = hu | (((unsigned int)__shfl_xor((int)hu, 16)) << 16);
    hi32 = (unsigned int)__shfl_xor((int)p32, 32);
    p01 = ((unsigned long long)hi32 << 32) | (unsigned long long)p32;
    hu = (unsigned int)f2bf(h10);
    p32 = hu | (((unsigned int)__shfl_xor((int)hu, 16)) << 16);
    hi32 = (unsigned int)__shfl_xor((int)p32, 32);
    p10 = ((unsigned long long)hi32 << 32) | (unsigned long long)p32;
    hu = (unsigned int)f2bf(h11);
    p32 = hu | (((unsigned int)__shfl_xor((int)hu, 16)) << 16);
    hi32 = (unsigned int)__shfl_xor((int)p32, 32);
    p11 = ((unsigned long long)hi32 << 32) | (unsigned long long)p32;

    if (lq == 0){
      unsigned long long* dst = &hp[(size_t)s * 4096];
      const int hb = wg * 8 + w * 2;          // (h>>2) base for this wave
      __hip_atomic_store(&dst[(size_t)lr * 128 + hb],           p00,
                         __ATOMIC_RELAXED, __HIP_MEMORY_SCOPE_AGENT);
      __hip_atomic_store(&dst[(size_t)lr * 128 + hb + 1],       p10,
                         __ATOMIC_RELAXED, __HIP_MEMORY_SCOPE_AGENT);
      __hip_atomic_store(&dst[(size_t)(16 + lr) * 128 + hb],     p01,
                         __ATOMIC_RELAXED, __HIP_MEMORY_SCOPE_AGENT);
      __hip_atomic_store(&dst[(size_t)(16 + lr) * 128 + hb + 1], p11,
                         __ATOMIC_RELAXED, __HIP_MEMORY_SCOPE_AGENT);
    }
    asm volatile("s_waitcnt vmcnt(0)" ::: "memory");  // data at coherence point
    __syncthreads();
    if (tid == 0)
      __hip_atomic_store(&tagsd[wg * 16], (unsigned int)(s + 1),
                         __ATOMIC_RELAXED, __HIP_MEMORY_SCOPE_AGENT);
  }
}

// ---- LayerNorm: wave per (b,t) row; reads hpub (chunked layout), writes hnorm ----
__global__ __launch_bounds__(256) void k_ln(
    const unsigned short* __restrict__ hbuf,
    const float* __restrict__ g, const float* __restrict__ bta,
    unsigned short* __restrict__ hnorm)
{
  int row = blockIdx.x * 4 + (threadIdx.x >> 6);
  int lane = threadIdx.x & 63;
  int b = row >> 9, t = row & 511;
  const int ch = t >> 6;
  // fwd: group 2*ch, local step = t - max(0, ch*64-WARM)
  int tsf = ch * 64 - WARM; if (tsf < 0) tsf = 0;
  const int gf = ch * 2, sf = t - tsf;
  // bwd: group 2*ch+1, local step = min(511, ch*64+63+WARM) - t
  int tsb = ch * 64 + 63 + WARM; if (tsb > 511) tsb = 511;
  const int gb = ch * 2 + 1, sb = tsb - t;
  const unsigned short* fsrc = hbuf + (((size_t)(gf * GSTEPS + sf) * 32 + b) * 512);
  const unsigned short* bsrc = hbuf + (((size_t)(gb * GSTEPS + sb) * 32 + b) * 512);
  uint4 u0 = *(const uint4*)&fsrc[lane * 8];
  uint4 u1 = *(const uint4*)&bsrc[lane * 8];
  const unsigned short* p0 = (const unsigned short*)&u0;
  const unsigned short* p1 = (const unsigned short*)&u1;
  float x[16];
  float sum = 0.f, ssq = 0.f;
  #pragma unroll
  for (int j = 0; j < 8; j++){ x[j] = bf2f(p0[j]); x[8 + j] = bf2f(p1[j]); }
  #pragma unroll
  for (int j = 0; j < 16; j++){ sum += x[j]; ssq += x[j] * x[j]; }
  #pragma unroll
  for (int off = 32; off; off >>= 1){ sum += __shfl_xor(sum, off); ssq += __shfl_xor(ssq, off); }
  float mean = sum * (1.0f / 1024.0f);
  float var = ssq * (1.0f / 1024.0f) - mean * mean;
  float rstd = rsqrtf(var + 1e-5f);
  unsigned short* dst = hnorm + (size_t)row * 1024;
  unsigned short o0[8], o1[8];
  #pragma unroll
  for (int j = 0; j < 8; j++){
    int i0 = lane * 8 + j, i1 = 512 + lane * 8 + j;
    o0[j] = f2bf((x[j]     - mean) * rstd * g[i0] + bta[i0]);
    o1[j] = f2bf((x[8 + j] - mean) * rstd * g[i1] + bta[i1]);
  }
  *(uint4*)&dst[lane * 8]       = *(const uint4*)o0;
  *(uint4*)&dst[512 + lane * 8] = *(const uint4*)o1;
}

// ---- emissions GEMM: (16384x1024)@(1024x32) + b_tag, no LDS, direct fragments ----
__global__ __launch_bounds__(256) void k_emis(
    const unsigned short* __restrict__ hnorm,
    const unsigned short* __restrict__ wtag,
    const float* __restrict__ btag,
    float* __restrict__ emis)
{
  const int m0 = blockIdx.x * 128;
  const int tid = threadIdx.x;
  const int lane = tid & 63, w = tid >> 6;
  const int lr = lane & 15, lq = lane >> 4;
  f32x4 acc[2][2];
  #pragma unroll
  for (int i = 0; i < 2; i++)
    #pragma unroll
    for (int j = 0; j < 2; j++) acc[i][j] = (f32x4){0.f,0.f,0.f,0.f};

  for (int kk = 0; kk < 32; ++kk){
    const int k0 = kk * 32;
    bf16x8 a[2], b[2];
    #pragma unroll
    for (int i = 0; i < 2; i++)
      a[i] = *(const bf16x8*)&hnorm[(size_t)(m0 + w * 32 + i * 16 + lr) * 1024 + k0 + lq * 8];
    #pragma unroll
    for (int j = 0; j < 2; j++)
      b[j] = *(const bf16x8*)&wtag[(size_t)(j * 16 + lr) * 1024 + k0 + lq * 8];
    #pragma unroll
    for (int i = 0; i < 2; i++)
      #pragma unroll
      for (int j = 0; j < 2; j++)
        acc[i][j] = __builtin_amdgcn_mfma_f32_16x16x32_bf16(a[i], b[j], acc[i][j], 0, 0, 0);
  }
  #pragma unroll
  for (int i = 0; i < 2; i++)
    #pragma unroll
    for (int j = 0; j < 2; j++){
      int col = j * 16 + lr;
      float bv = btag[col];
      #pragma unroll
      for (int r = 0; r < 4; r++){
        int row = m0 + w * 32 + i * 16 + lq * 4 + r;
        emis[(size_t)row * 32 + col] = acc[i][j][r] + bv;
      }
    }
}

// ---- CRF log-likelihood (wave per batch) ----
__global__ __launch_bounds__(64) void k_crf(
    const float* __restrict__ emis, const int* __restrict__ tags,
    const int* __restrict__ mask, const float* __restrict__ trans,
    const float* __restrict__ start_t, const float* __restrict__ end_t,
    float* __restrict__ llh)
{
  const int b = blockIdx.x;
  const int lane = threadIdx.x;
  __shared__ float tr[32 * 33];
  __shared__ float al[32];
  #pragma unroll
  for (int it = 0; it < 16; ++it){
    int c = lane + 64 * it;
    tr[(c >> 5) * 33 + (c & 31)] = trans[c];
  }
  __syncthreads();
  float part = 0.0f; int cnt = 0;
  for (int t = lane; t < 512; t += 64){
    int tg = tags[b * 512 + t];
    cnt += mask[b * 512 + t];
    if (t == 0){
      part += start_t[tg] + emis[((size_t)b * 512) * 32 + tg];
    } else {
      int tp = tags[b * 512 + t - 1];
      float mf = (float)mask[b * 512 + t];
      part += (tr[tp * 33 + tg] + emis[((size_t)b * 512 + t) * 32 + tg]) * mf;
    }
  }
  #pragma unroll
  for (int off = 32; off; off >>= 1){ part += __shfl_xor(part, off); cnt += __shfl_xor(cnt, off); }
  int col = lane & 31;
  if (lane < 32) al[lane] = start_t[lane] + emis[((size_t)b * 512) * 32 + lane];
  __syncthreads();
  for (int t = 1; t < 512; ++t){
    float e = emis[((size_t)b * 512 + t) * 32 + col];
    int mk = mask[b * 512 + t];
    float m = -1e30f;
    #pragma unroll
    for (int i = 0; i < 32; i++) m = fmaxf(m, al[i] + tr[i * 33 + col]);
    float sexp = 0.0f;
    #pragma unroll
    for (int i = 0; i < 32; i++) sexp += __expf(al[i] + tr[i * 33 + col] - m);
    float nxt = e + m + __logf(sexp);
    float na = mk ? nxt : al[col];
    __syncthreads();
    if (lane < 32) al[lane] = na;
    __syncthreads();
  }
  float v = (lane < 32) ? (al[lane] + end_t[lane]) : -1e30f;
  float mv = v;
  #pragma unroll
  for (int off = 32; off; off >>= 1) mv = fmaxf(mv, __shfl_xor(mv, off));
  float se = (lane < 32) ? __expf(v - mv) : 0.0f;
  #pragma unroll
  for (int off = 32; off; off >>= 1) se += __shfl_xor(se, off);
  if (lane == 0){
    int last_idx = cnt - 1;
    int lt = tags[b * 512 + last_idx];
    float num = part + end_t[lt];
    float logZ = mv + __logf(se);
    llh[b] = num - logZ;
  }
}

__global__ void k_final(const float* __restrict__ llh, const unsigned int* __restrict__ tflag,
                        float* __restrict__ out){
  int lane = threadIdx.x;
  float v = (lane < 32) ? llh[lane] : 0.0f;
  #pragma unroll
  for (int off = 32; off; off >>= 1) v += __shfl_xor(v, off);
  if (lane == 0) out[0] = -(v * (1.0f / 32.0f)) + (tflag[0] ? 1.0e6f : 0.0f);
}

extern "C" void kernel_launch(void* const* d_in, const int* in_sizes, int n_in,
                              void* d_out, int out_size, void* d_ws, size_t ws_size,
                              hipStream_t stream)
{
  (void)in_sizes; (void)n_in; (void)out_size;
  const float* emb   = (const float*)d_in[0];
  const int*   tags  = (const int*)d_in[1];
  const int*   amask = (const int*)d_in[2];
  const float* wihf  = (const float*)d_in[3];
  const float* whhf  = (const float*)d_in[4];
  const float* bf_   = (const float*)d_in[5];
  const float* wihb  = (const float*)d_in[6];
  const float* whhb  = (const float*)d_in[7];
  const float* bb_   = (const float*)d_in[8];
  const float* lng   = (const float*)d_in[9];
  const float* lnb   = (const float*)d_in[10];
  const float* wtag  = (const float*)d_in[11];
  const float* btag  = (const float*)d_in[12];
  const float* trans = (const float*)d_in[13];
  const float* stt   = (const float*)d_in[14];
  const float* endt  = (const float*)d_in[15];

  unsigned char* wsp = (unsigned char*)d_ws;
  size_t off = 0;
  auto alloc = [&](size_t bytes) -> void* {
    void* p = wsp + off; off += (bytes + 255) & ~(size_t)255; return p;
  };
  unsigned short* xpf   = (unsigned short*)alloc(33554432ull * 2);  // 64MB, reused as hnorm
  unsigned short* xpb   = (unsigned short*)alloc(33554432ull * 2);  // 64MB
  unsigned long long* hpub = (unsigned long long*)alloc(16ull * GSTEPS * 4096 * 8);  // ~58.7MB
  unsigned short* wtagb = (unsigned short*)alloc(32768ull * 2);
  float* emis = (float*)alloc(524288ull * 4);
  float* llh  = (float*)alloc(64 * 4);
  unsigned int* sync = (unsigned int*)alloc(16 * 64 * 64 + 256);  // [group][16] 64B tags + tflag
  unsigned short* hnorm = xpf;  // alias: xp dead after k_lstm
  unsigned int* tflag = sync + 16 * 64 * 16;
  // bf16 pre-convert buffers aliased into hpub (dead until k_lstm):
  // Xb 32MB @ +0, Wfb 4MB @ +32MB, Wbb 4MB @ +36MB  (hpub is 58.7MB)
  unsigned short* Xb  = (unsigned short*)hpub;
  unsigned short* Wfb = (unsigned short*)((unsigned char*)hpub + 33554432ull);
  unsigned short* Wbb = (unsigned short*)((unsigned char*)hpub + 37748736ull);

  if (off > ws_size){
    k_sentinel<<<1, 1, 0, stream>>>((float*)d_out);
    return;
  }

  hipMemsetAsync(sync, 0, 16 * 64 * 64 + 256, stream);
  k_convert8<<<2048, 256, 0, stream>>>(emb,  Xb,    2097152);
  k_convert8<<<1024, 256, 0, stream>>>(wihf, Wfb,    262144);
  k_convert8<<<1024, 256, 0, stream>>>(wihb, Wbb,    262144);
  k_convert8<<<16,   256, 0, stream>>>(wtag, wtagb,    4096);
  k_xproj<<<dim3(128, 16, 2), 256, 0, stream>>>(Xb, Wfb, Wbb, bf_, bb_, xpf, xpb);
  k_lstm<<<256, 256, 0, stream>>>(xpf, xpb, whhf, whhb, hpub, sync, tflag);
  k_ln<<<4096, 256, 0, stream>>>((const unsigned short*)hpub, lng, lnb, hnorm);
  k_emis<<<128, 256, 0, stream>>>(hnorm, wtagb, btag, emis);
  k_crf<<<32, 64, 0, stream>>>(emis, tags, amask, trans, stt, endt, llh);
  k_final<<<1, 64, 0, stream>>>(llh, tflag, (float*)d_out);
}